// Round 1
// baseline (74.957 us; speedup 1.0000x reference)
//
#include <hip/hip_runtime.h>
#include <math.h>

namespace {

constexpr int   MTOT = 4096;       // total nodes
constexpr float H    = 0.1f;

// W_FACTORS = sqrt((0.5^2 + sigma^2)/2), sigma in {0.4, 0.8, 1.2, 1.6}
constexpr float W0 = 0.45276925690687087f;
constexpr float W1 = 0.66708320320631664f;
constexpr float W2 = 0.91923881554251174f;
constexpr float W3 = 1.18532695911296985f;

constexpr float KCOUL   = 14.399645478425669f;  // e*1e10/eps0/(4*pi)
constexpr float HALF_L1 = 2.8867513459481287f;  // 0.5*sqrt(3)/0.3
constexpr float SQRTPI  = 1.7724538509055159f;

// A&S 7.1.25 erf (|err|<=2.5e-5): erf(k d) = 1 - t(a1+a2 t+a3 t^2) * 2^(c2 d^2)
// with t = 1/(1 + pk d), pk = 0.47047*k, c2 = -k^2*log2(e).  k_r = 0.5/W_r.
constexpr float PK0 = 0.5195472f, PK1 = 0.3526314f, PK2 = 0.2559019f, PK3 = 0.1984558f;
constexpr float C20 = -1.7593842f, C21 = -0.8105028f, C22 = -0.4268329f, C23 = -0.2567073f;
constexpr float EA1 = 0.3480242f, EA2 = -0.0958798f, EA3 = 0.7478556f;
constexpr float RCP_H = 9.9999000f, RCP_HS2 = 7.0710178f, RCP_2H = 4.9999750f;

// KQ_r = -0.2*(2/sqrt(pi))*k_r : coefficient of the exp term in the dipole Gt.
// Note 2^(c2 d^2) == exp(-k^2 d^2), so the same exp2 feeds erf AND Gt.
constexpr float KQ0 = -0.24921720f, KQ1 = -0.16915128f, KQ2 = -0.12275067f, KQ3 = -0.09519549f;

// tier radii: near if any lane d<2; saturated (all erf==1) if all lanes d>7.03
constexpr float NEAR2 = 4.0f;
constexpr float SAT2  = 49.4f;

__device__ __forceinline__ float fast_rcp(float x)  { return __builtin_amdgcn_rcpf(x); }
__device__ __forceinline__ float fast_rsq(float x)  { return __builtin_amdgcn_rsqf(x); }
__device__ __forceinline__ float fast_exp2(float x) { return __builtin_amdgcn_exp2f(x); }

// q = erfc-part of A&S 7.1.25 (epilogue helper)
__device__ __forceinline__ float erf_q(float d, float d2, float pk, float c2) {
  float t = fast_rcp(__builtin_fmaf(d, pk, 1.0f));
  float poly = t * __builtin_fmaf(t, __builtin_fmaf(t, EA3, EA2), EA1);
  return poly * fast_exp2(d2 * c2);
}

// project (7 x 4) site-features S[j*4+r] -> 16 outputs
__device__ __forceinline__ float project_one(const float* S, int k) {
  if (k < 4) return S[k];
  int q = k - 4;
  int r = q / 3;
  int comp = q - 3 * r;
  int j1, j2;
  if (comp == 0)      { j1 = 2; j2 = 5; }
  else if (comp == 1) { j1 = 3; j2 = 6; }
  else                { j1 = 1; j2 = 4; }
  return HALF_L1 * (S[j1 * 4 + r] - S[j2 * 4 + r]);
}

__device__ __forceinline__ unsigned spread3(int v) {
  return (unsigned)((v & 1) | ((v & 2) << 2) | ((v & 4) << 4));
}

// grid: 256 blocks = 32 graphs x 8 node-blocks; block: 896 thr = 112 sites x 8 chunks.
// Morton-sorted nodes; 3-tier source loop, ALL tiers computed in-register via
// A&S 7.1.25 (no LDS interpolation tables -> no data-dependent LDS gathers).
__global__ __launch_bounds__(896, 4) void es_main(
    const float* __restrict__ sf,   // (4096, 4)
    const float* __restrict__ pos,  // (4096, 3)
    float* __restrict__ out)        // [0:65536) features, [65536:131072) self_terms
{
  __shared__ float4   s_pos4[128];     // node centers (SORTED)
  __shared__ float4   s_chg4[128];     // prescaled charges {s0,5s3,5s1,5s2} (SORTED)
  __shared__ int      s_orig[128];     // sorted slot -> original node
  __shared__ unsigned s_key[128];
  __shared__ float4   s_part[8 * 112]; // per-chunk partial sums
  __shared__ float    s_feat[448];
  __shared__ float    s_self[448];

  const int b   = blockIdx.x;
  const int g   = b >> 3;    // graph
  const int nb  = b & 7;     // node-block (sorted space)
  const int tid = threadIdx.x;

  // ---- phase 1: node data + Morton keys ----
  float px = 0.f, py = 0.f, pz = 0.f;
  float4 myc = make_float4(0.f, 0.f, 0.f, 0.f);
  if (tid < 128) {
    const float* p = pos + (size_t)(g * 128 + tid) * 3;
    px = p[0]; py = p[1]; pz = p[2];
    const float4 s = ((const float4*)sf)[g * 128 + tid];
    myc = make_float4(s.x, 5.0f * s.w, 5.0f * s.y, 5.0f * s.z);
    int cx = (int)((px + 16.0f) * 0.25f); cx = (cx < 0) ? 0 : (cx > 7 ? 7 : cx);
    int cy = (int)((py + 16.0f) * 0.25f); cy = (cy < 0) ? 0 : (cy > 7 ? 7 : cy);
    int cz = (int)((pz + 16.0f) * 0.25f); cz = (cz < 0) ? 0 : (cz > 7 ? 7 : cz);
    unsigned mort = spread3(cx) | (spread3(cy) << 1) | (spread3(cz) << 2);
    s_key[tid] = (mort << 7) | (unsigned)tid;
  }
  __syncthreads();

  // ---- phase 2: rank-sort scatter ----
  if (tid < 128) {
    const unsigned mykey = s_key[tid];
    int rank = 0;
    for (int t = 0; t < 128; ++t) rank += (s_key[t] < mykey) ? 1 : 0;
    s_pos4[rank] = make_float4(px, py, pz, 0.0f);
    s_chg4[rank] = myc;
    s_orig[rank] = tid;
  }
  __syncthreads();

  // ---- per-thread target site (sorted space) ----
  const int site_local = tid % 112;
  const int chunk      = tid / 112;          // 0..7, 16 source nodes each
  const int sl   = nb * 112 + site_local;
  const int jown = (sl * 9363) >> 16;        // own node slot
  const int aoff = sl - jown * 7;

  const float4 cp = s_pos4[jown];
  const float tx = cp.x + ((aoff == 1) ? H : (aoff == 4) ? -H : 0.0f);
  const float ty = cp.y + ((aoff == 2) ? H : (aoff == 5) ? -H : 0.0f);
  const float tz = cp.z + ((aoff == 3) ? H : (aoff == 6) ? -H : 0.0f);

  float a0 = 0.f, a1 = 0.f, a2 = 0.f, a3 = 0.f, Ssat = 0.f;

  // exact per-subsite contribution, valid at ALL d (A&S 7.1.25 in registers)
  auto acc_full = [&](float d2raw, float c) {
    const float d2 = fmaxf(d2raw, 1e-12f);
    const float rd = fast_rsq(d2);
    const float d  = d2 * rd;
    const float cv = c * rd;
    const float t0 = fast_rcp(__builtin_fmaf(d, PK0, 1.0f));
    const float t1 = fast_rcp(__builtin_fmaf(d, PK1, 1.0f));
    const float t2 = fast_rcp(__builtin_fmaf(d, PK2, 1.0f));
    const float t3 = fast_rcp(__builtin_fmaf(d, PK3, 1.0f));
    const float q0 = t0 * __builtin_fmaf(t0, __builtin_fmaf(t0, EA3, EA2), EA1) * fast_exp2(d2 * C20);
    const float q1 = t1 * __builtin_fmaf(t1, __builtin_fmaf(t1, EA3, EA2), EA1) * fast_exp2(d2 * C21);
    const float q2 = t2 * __builtin_fmaf(t2, __builtin_fmaf(t2, EA3, EA2), EA1) * fast_exp2(d2 * C22);
    const float q3 = t3 * __builtin_fmaf(t3, __builtin_fmaf(t3, EA3, EA2), EA1) * fast_exp2(d2 * C23);
    a0 = __builtin_fmaf(cv, 1.0f - q0, a0);
    a1 = __builtin_fmaf(cv, 1.0f - q1, a1);
    a2 = __builtin_fmaf(cv, 1.0f - q2, a2);
    a3 = __builtin_fmaf(cv, 1.0f - q3, a3);
  };

  const int j0 = chunk * 16;
  for (int jj = 0; jj < 16; ++jj) {
    const int j = j0 + jj;
    const float4 p4 = s_pos4[j];   // wave-uniform j -> LDS broadcast, no conflicts
    const float4 c4 = s_chg4[j];
    const float vx = tx - p4.x;
    const float vy = ty - p4.y;
    const float vz = tz - p4.z;
    const float v2 = __builtin_fmaf(vx, vx, __builtin_fmaf(vy, vy, vz * vz));
    if (__any(v2 < NEAR2)) {
      // NEAR: exact 7-site path; own-site masking
      const float w2 = v2 + 0.01f;
      const bool own = (j == jown);
      acc_full(v2,                            (own & (aoff == 0)) ? 0.0f :  c4.x);
      acc_full(__builtin_fmaf(vx, -0.2f, w2), (own & (aoff == 1)) ? 0.0f :  c4.y);
      acc_full(__builtin_fmaf(vy, -0.2f, w2), (own & (aoff == 2)) ? 0.0f :  c4.z);
      acc_full(__builtin_fmaf(vz, -0.2f, w2), (own & (aoff == 3)) ? 0.0f :  c4.w);
      acc_full(__builtin_fmaf(vx,  0.2f, w2), (own & (aoff == 4)) ? 0.0f : -c4.y);
      acc_full(__builtin_fmaf(vy,  0.2f, w2), (own & (aoff == 5)) ? 0.0f : -c4.z);
      acc_full(__builtin_fmaf(vz,  0.2f, w2), (own & (aoff == 6)) ? 0.0f : -c4.w);
    } else if (__any(v2 < SAT2)) {
      // MID: monopole + dipole, fully analytic.
      // contribution_r = erf_r * P + KQ_r * x_r * Qc,  x_r = 2^(C2_r * d^2)
      const float rd  = fast_rsq(v2);
      const float d   = v2 * rd;
      const float dot = __builtin_fmaf(c4.y, vx, __builtin_fmaf(c4.z, vy, c4.w * vz));
      const float rd2 = rd * rd;
      const float P   = rd * __builtin_fmaf(0.2f * dot, rd2, c4.x);  // c0/d + 0.2*dot/d^3
      const float Qc  = dot * rd2;
      const float t0 = fast_rcp(__builtin_fmaf(d, PK0, 1.0f));
      const float t1 = fast_rcp(__builtin_fmaf(d, PK1, 1.0f));
      const float t2 = fast_rcp(__builtin_fmaf(d, PK2, 1.0f));
      const float t3 = fast_rcp(__builtin_fmaf(d, PK3, 1.0f));
      const float x0 = fast_exp2(v2 * C20);
      const float x1 = fast_exp2(v2 * C21);
      const float x2 = fast_exp2(v2 * C22);
      const float x3 = fast_exp2(v2 * C23);
      const float q0 = t0 * __builtin_fmaf(t0, __builtin_fmaf(t0, EA3, EA2), EA1) * x0;
      const float q1 = t1 * __builtin_fmaf(t1, __builtin_fmaf(t1, EA3, EA2), EA1) * x1;
      const float q2 = t2 * __builtin_fmaf(t2, __builtin_fmaf(t2, EA3, EA2), EA1) * x2;
      const float q3 = t3 * __builtin_fmaf(t3, __builtin_fmaf(t3, EA3, EA2), EA1) * x3;
      a0 = __builtin_fmaf(KQ0 * x0, Qc, __builtin_fmaf(-q0, P, a0 + P));
      a1 = __builtin_fmaf(KQ1 * x1, Qc, __builtin_fmaf(-q1, P, a1 + P));
      a2 = __builtin_fmaf(KQ2 * x2, Qc, __builtin_fmaf(-q2, P, a2 + P));
      a3 = __builtin_fmaf(KQ3 * x3, Qc, __builtin_fmaf(-q3, P, a3 + P));
    } else {
      // SAT: all lanes fully saturated -> analytic monopole + dipole (erf==1)
      const float rd  = fast_rsq(v2);
      const float dot = __builtin_fmaf(c4.y, vx, __builtin_fmaf(c4.z, vy, c4.w * vz));
      Ssat = __builtin_fmaf(c4.x, rd, Ssat);
      Ssat = __builtin_fmaf(0.2f * dot, rd * rd * rd, Ssat);
    }
  }
  a0 += Ssat; a1 += Ssat; a2 += Ssat; a3 += Ssat;

  s_part[chunk * 112 + site_local] = make_float4(a0, a1, a2, a3);
  __syncthreads();

  // ---- reduce chunks + self term + own-node correction (cancels to +c_a*diag) ----
  if (tid < 448) {
    const int site = tid >> 2;   // 0..111 (sorted space)
    const int r    = tid & 3;
    const float* pf = (const float*)s_part;
    float tot = 0.f;
#pragma unroll
    for (int c = 0; c < 8; ++c) tot += pf[c * 448 + tid];

    const float w  = (r == 0) ? W0  : (r == 1) ? W1  : (r == 2) ? W2  : W3;
    const float pk = (r == 0) ? PK0 : (r == 1) ? PK1 : (r == 2) ? PK2 : PK3;
    const float c2 = (r == 0) ? C20 : (r == 1) ? C21 : (r == 2) ? C22 : C23;
    const float diag = fast_rcp(w * SQRTPI);
    const float ph1 = (1.f - erf_q(0.1f,        0.01f, pk, c2)) * RCP_H;
    const float ph2 = (1.f - erf_q(0.14142136f, 0.02f, pk, c2)) * RCP_HS2;
    const float ph3 = (1.f - erf_q(0.2f,        0.04f, pk, c2)) * RCP_2H;

    const int jn = (site * 9363) >> 16;
    const int ba = site - jn * 7;
    const float4 c4 = s_chg4[nb * 16 + jn];
    float selfSum = 0.f, ca = 0.f;
#pragma unroll
    for (int i = 0; i < 7; ++i) {
      const float ci = (i == 0) ?  c4.x : (i == 1) ?  c4.y : (i == 2) ?  c4.z :
                       (i == 3) ?  c4.w : (i == 4) ? -c4.y : (i == 5) ? -c4.z : -c4.w;
      float ph;
      if (i == ba)                             ph = diag;
      else if (i == 0 || ba == 0)              ph = ph1;
      else if ((i - ba == 3) || (ba - i == 3)) ph = ph3;
      else                                     ph = ph2;
      selfSum = __builtin_fmaf(ci, ph, selfSum);
      if (i == ba) ca = ci;
    }
    s_self[tid] = KCOUL * selfSum;
    s_feat[tid] = KCOUL * __builtin_fmaf(ca, diag, tot);
  }
  __syncthreads();

  // ---- projection + write (map sorted node -> original id) ----
  if (tid < 256) {
    const int node = tid >> 4;
    const int k    = tid & 15;
    const int m    = g * 128 + s_orig[nb * 16 + node];
    float vf = project_one(&s_feat[node * 28], k);
    float vs = project_one(&s_self[node * 28], k);
    out[m * 16 + k]             = vf;
    out[MTOT * 16 + m * 16 + k] = vs;
  }
}

} // namespace

extern "C" void kernel_launch(void* const* d_in, const int* in_sizes, int n_in,
                              void* d_out, int out_size, void* d_ws, size_t ws_size,
                              hipStream_t stream) {
  const float* sf  = (const float*)d_in[0];   // source_feats (4096,1,4)
  const float* pos = (const float*)d_in[1];   // node_positions (4096,3)
  float* out = (float*)d_out;
  es_main<<<256, 896, 0, stream>>>(sf, pos, out);
}